// Round 6
// baseline (636.522 us; speedup 1.0000x reference)
//
#include <hip/hip_runtime.h>
#include <hip/hip_bf16.h>
#include <math.h>

typedef __attribute__((ext_vector_type(8))) short bf16x8;
typedef __attribute__((ext_vector_type(4))) float f32x4;
typedef unsigned short ushort_t;

#define T_SEQ 4096
#define C_DIM 1024
#define NH 16
#define HD 64

__device__ __forceinline__ ushort_t f2b(float f) {
  union { float f; unsigned u; } v; v.f = f;
  unsigned r = v.u + 0x7FFF + ((v.u >> 16) & 1);   // RNE
  return (ushort_t)(r >> 16);
}

// ---------------- cast + transpose: W[K][N] fp32 -> WT[N][K] bf16 -----------
__global__ __launch_bounds__(256) void cast_transpose(const float* __restrict__ W,
                                                      ushort_t* __restrict__ WT,
                                                      int K, int N) {
  __shared__ ushort_t tile[32][40];
  int n0 = blockIdx.x * 32, k0 = blockIdx.y * 32;
  int t = threadIdx.x;
  int kl = t >> 3, nl = (t & 7) * 4;
  float4 v = *(const float4*)(W + (size_t)(k0 + kl) * N + n0 + nl);
  ushort4 c;
  c.x = f2b(v.x); c.y = f2b(v.y); c.z = f2b(v.z); c.w = f2b(v.w);
  *(ushort4*)&tile[kl][nl] = c;
  __syncthreads();
  int nl2 = t >> 3, kl2 = (t & 7) * 4;
  ushort4 o;
  o.x = tile[kl2 + 0][nl2];
  o.y = tile[kl2 + 1][nl2];
  o.z = tile[kl2 + 2][nl2];
  o.w = tile[kl2 + 3][nl2];
  *(ushort4*)(WT + (size_t)(n0 + nl2) * K + k0 + kl2) = o;
}

// ---------------- LayerNorm: fp32 [rows][1024] -> bf16 ----------------------
__global__ __launch_bounds__(256) void ln_kernel(const float* __restrict__ x,
                                                 const float* __restrict__ g,
                                                 const float* __restrict__ b,
                                                 ushort_t* __restrict__ out) {
  int row = blockIdx.x;
  int tid = threadIdx.x;
  float4 v = ((const float4*)(x + (size_t)row * C_DIM))[tid];
  float s  = v.x + v.y + v.z + v.w;
  float sq = v.x*v.x + v.y*v.y + v.z*v.z + v.w*v.w;
  #pragma unroll
  for (int m = 32; m >= 1; m >>= 1) {
    s  += __shfl_down(s, m, 64);
    sq += __shfl_down(sq, m, 64);
  }
  __shared__ float red[8];
  int wid = tid >> 6, lane = tid & 63;
  if (lane == 0) { red[wid] = s; red[wid + 4] = sq; }
  __syncthreads();
  s  = red[0] + red[1] + red[2] + red[3];
  sq = red[4] + red[5] + red[6] + red[7];
  float mu   = s * (1.0f / C_DIM);
  float var  = sq * (1.0f / C_DIM) - mu * mu;
  float rstd = rsqrtf(var + 1e-5f);
  float4 gg = ((const float4*)g)[tid];
  float4 bb = ((const float4*)b)[tid];
  ushort4 o;
  o.x = f2b((v.x - mu) * rstd * gg.x + bb.x);
  o.y = f2b((v.y - mu) * rstd * gg.y + bb.y);
  o.z = f2b((v.z - mu) * rstd * gg.z + bb.z);
  o.w = f2b((v.w - mu) * rstd * gg.w + bb.w);
  ((ushort4*)(out + (size_t)row * C_DIM))[tid] = o;
}

// ---------------- bf16 MFMA GEMM, m97 structure (unchanged) -----------------
template<bool GELU, bool OUT_F32, bool RES>
__global__ __launch_bounds__(256) void gemm_bt(
    const ushort_t* __restrict__ A, const ushort_t* __restrict__ BT,
    const float* __restrict__ bias, const float* __restrict__ res,
    float* __restrict__ outF, ushort_t* __restrict__ outB,
    int M, int N, int K) {
  __shared__ ushort_t As[128][64];
  __shared__ ushort_t Bs[128][64];
  int tid  = threadIdx.x;
  int lane = tid & 63, w = tid >> 6;
  int wr = (w >> 1) * 64, wc = (w & 1) * 64;
  int brow = blockIdx.y * 128, bcol = blockIdx.x * 128;
  int l15 = lane & 15, lg = lane >> 4;

  f32x4 acc[4][4];
  #pragma unroll
  for (int m = 0; m < 4; ++m)
    #pragma unroll
    for (int n = 0; n < 4; ++n)
      acc[m][n] = (f32x4){0.f, 0.f, 0.f, 0.f};

  for (int k0 = 0; k0 < K; k0 += 64) {
    #pragma unroll
    for (int it = 0; it < 4; ++it) {
      int idx = it * 256 + tid;
      int r = idx >> 3, c = (idx & 7) * 8;
      __builtin_amdgcn_global_load_lds(
          (const __attribute__((address_space(1))) unsigned*)(A + (size_t)(brow + r) * K + k0 + c),
          (__attribute__((address_space(3))) unsigned*)&As[0][0] + idx * 4,
          16, 0, 0);
    }
    #pragma unroll
    for (int it = 0; it < 4; ++it) {
      int idx = it * 256 + tid;
      int r = idx >> 3, c = (idx & 7) * 8;
      __builtin_amdgcn_global_load_lds(
          (const __attribute__((address_space(1))) unsigned*)(BT + (size_t)(bcol + r) * K + k0 + c),
          (__attribute__((address_space(3))) unsigned*)&Bs[0][0] + idx * 4,
          16, 0, 0);
    }
    __syncthreads();
    #pragma unroll
    for (int half = 0; half < 2; ++half) {
      bf16x8 af[4], bfr[4];
      #pragma unroll
      for (int m = 0; m < 4; ++m)
        af[m] = *(const bf16x8*)&As[wr + m * 16 + l15][half * 32 + lg * 8];
      #pragma unroll
      for (int n = 0; n < 4; ++n)
        bfr[n] = *(const bf16x8*)&Bs[wc + n * 16 + l15][half * 32 + lg * 8];
      #pragma unroll
      for (int m = 0; m < 4; ++m)
        #pragma unroll
        for (int n = 0; n < 4; ++n)
          acc[m][n] = __builtin_amdgcn_mfma_f32_16x16x32_bf16(af[m], bfr[n], acc[m][n], 0, 0, 0);
    }
    __syncthreads();
  }

  #pragma unroll
  for (int m = 0; m < 4; ++m) {
    int row0 = brow + wr + m * 16 + lg * 4;
    #pragma unroll
    for (int n = 0; n < 4; ++n) {
      int col = bcol + wc + n * 16 + l15;
      float bv = bias[col];
      #pragma unroll
      for (int r = 0; r < 4; ++r) {
        int row = row0 + r;
        float v = acc[m][n][r] + bv;
        if (RES)  v += res[(size_t)row * N + col];
        if (GELU) v = 0.5f * v * (1.0f + erff(v * 0.70710678118f));
        if (OUT_F32) outF[(size_t)row * N + col] = v;
        else         outB[(size_t)row * N + col] = f2b(v);
      }
    }
  }
}

// ---------------- causal flash attention, 2-phase pipelined -----------------
// QBLK=128 (4 waves x 32 rows), KVBLK=64, double-buffered K and V.
// Ks[b][r][c'] holds K[r][c] with chunk swizzle c' (pre-swizzled gload_lds src).
// Vs[b][d][kv'] holds V^T, kv' = kv ^ ((d&7)<<3) (reg-stage + swizzled scatter).
// Per iteration: issue next K gload_lds + next V reg loads -> compute current
// -> scatter V regs -> one barrier.
__global__ __launch_bounds__(256) void attn_kernel(const ushort_t* __restrict__ qkv,
                                                   ushort_t* __restrict__ out) {
  __shared__ ushort_t Ks[2][64][64];
  __shared__ ushort_t Vs[2][64][64];
  __shared__ ushort_t Pb[4][2][16][72];   // [wave][rowfrag][qrow][kv]
  int h  = blockIdx.y;
  int qb = gridDim.x - 1 - blockIdx.x;    // 0..31, heavy blocks first
  int tid = threadIdx.x, lane = tid & 63, w = tid >> 6;
  int l15 = lane & 15, lg = lane >> 4;

  // Q fragments: 2 row-frags x 2 k-chunks
  bf16x8 qf[2][2];
  #pragma unroll
  for (int rf = 0; rf < 2; ++rf) {
    int qrow = qb * 128 + w * 32 + rf * 16 + l15;
    const ushort_t* qp = qkv + (size_t)qrow * 3072 + h * 64;
    qf[rf][0] = *(const bf16x8*)(qp + lg * 8);
    qf[rf][1] = *(const bf16x8*)(qp + 32 + lg * 8);
  }

  float m_r[2][4], l_r[2][4];
  f32x4 o[2][4];
  #pragma unroll
  for (int rf = 0; rf < 2; ++rf) {
    #pragma unroll
    for (int r = 0; r < 4; ++r) { m_r[rf][r] = -1e30f; l_r[rf][r] = 0.f; }
    #pragma unroll
    for (int f = 0; f < 4; ++f) o[rf][f] = (f32x4){0.f, 0.f, 0.f, 0.f};
  }

  int kvq = tid & 63, vd0 = (tid >> 6) * 16;   // V staging assignment
  bf16x8 vreg[2];

  // ---- staging helpers ----
  auto stage_K = [&](int s, int buf) {
    const ushort_t* kbase = qkv + (size_t)(s * 64) * 3072 + h * 64 + 1024;
    #pragma unroll
    for (int it = 0; it < 2; ++it) {
      int idx = it * 256 + tid;            // 0..511: 64 rows x 8 chunks
      int r = idx >> 3, ch = idx & 7;
      int srcc = (ch ^ (r & 7)) * 8;
      __builtin_amdgcn_global_load_lds(
          (const __attribute__((address_space(1))) unsigned*)(kbase + (size_t)r * 3072 + srcc),
          (__attribute__((address_space(3))) unsigned*)&Ks[buf][0][0] + idx * 4,
          16, 0, 0);
    }
  };
  auto load_V = [&](int s) {
    const ushort_t* vbase = qkv + (size_t)(s * 64) * 3072 + h * 64 + 2048;
    vreg[0] = *(const bf16x8*)(vbase + (size_t)kvq * 3072 + vd0);
    vreg[1] = *(const bf16x8*)(vbase + (size_t)kvq * 3072 + vd0 + 8);
  };
  auto scatter_V = [&](int buf) {
    #pragma unroll
    for (int e = 0; e < 8; ++e) {
      Vs[buf][vd0 + e][kvq ^ (e << 3)]     = ((ushort_t*)&vreg[0])[e];
      Vs[buf][vd0 + 8 + e][kvq ^ (e << 3)] = ((ushort_t*)&vreg[1])[e];
    }
  };

  int s_last = 2 * qb + 1;
  // prologue: stage tile 0 into buffer 0
  stage_K(0, 0);
  load_V(0);
  scatter_V(0);
  __syncthreads();

  int cur = 0;
  for (int s = 0; s <= s_last; ++s) {
    // ---- issue next-tile loads (latency hides under compute) ----
    if (s < s_last) {
      stage_K(s + 1, cur ^ 1);
      load_V(s + 1);
    }

    // ---- S = Q K^T for both row-frags (K frags hoisted) ----
    bf16x8 kf[4][2];
    #pragma unroll
    for (int f = 0; f < 4; ++f) {
      int row = f * 16 + l15;
      kf[f][0] = *(const bf16x8*)&Ks[cur][row][((0 + lg) ^ (row & 7)) * 8];
      kf[f][1] = *(const bf16x8*)&Ks[cur][row][((4 + lg) ^ (row & 7)) * 8];
    }
    float p[2][4][4];
    #pragma unroll
    for (int rf = 0; rf < 2; ++rf) {
      #pragma unroll
      for (int f = 0; f < 4; ++f) {
        f32x4 a = (f32x4){0.f, 0.f, 0.f, 0.f};
        a = __builtin_amdgcn_mfma_f32_16x16x32_bf16(qf[rf][0], kf[f][0], a, 0, 0, 0);
        a = __builtin_amdgcn_mfma_f32_16x16x32_bf16(qf[rf][1], kf[f][1], a, 0, 0, 0);
        #pragma unroll
        for (int r = 0; r < 4; ++r) {
          float v = a[r] * 0.125f;
          if (s >= 2 * qb) {   // only last two tiles can touch the diagonal
            int rl = qb * 128 + w * 32 + rf * 16 + lg * 4 + r;
            int cl = s * 64 + f * 16 + l15;
            if (cl > rl) v = -1e30f;
          }
          p[rf][f][r] = v;
        }
      }
    }

    // ---- online softmax per row-frag ----
    #pragma unroll
    for (int rf = 0; rf < 2; ++rf) {
      #pragma unroll
      for (int r = 0; r < 4; ++r) {
        float mx = fmaxf(fmaxf(p[rf][0][r], p[rf][1][r]), fmaxf(p[rf][2][r], p[rf][3][r]));
        #pragma unroll
        for (int off = 1; off < 16; off <<= 1) mx = fmaxf(mx, __shfl_xor(mx, off, 64));
        float mn = fmaxf(m_r[rf][r], mx);
        float sc = __expf(m_r[rf][r] - mn);
        float sum = 0.f;
        #pragma unroll
        for (int f = 0; f < 4; ++f) { p[rf][f][r] = __expf(p[rf][f][r] - mn); sum += p[rf][f][r]; }
        #pragma unroll
        for (int off = 1; off < 16; off <<= 1) sum += __shfl_xor(sum, off, 64);
        l_r[rf][r] = l_r[rf][r] * sc + sum;
        m_r[rf][r] = mn;
        #pragma unroll
        for (int f = 0; f < 4; ++f) o[rf][f][r] *= sc;
      }
    }

    // ---- P -> wave-private LDS, then O += P V (per row-frag) ----
    #pragma unroll
    for (int rf = 0; rf < 2; ++rf) {
      #pragma unroll
      for (int f = 0; f < 4; ++f)
        #pragma unroll
        for (int r = 0; r < 4; ++r)
          Pb[w][rf][lg * 4 + r][f * 16 + l15] = f2b(p[rf][f][r]);
      #pragma unroll
      for (int kc = 0; kc < 2; ++kc) {
        bf16x8 pf = *(const bf16x8*)&Pb[w][rf][l15][kc * 32 + lg * 8];
        #pragma unroll
        for (int f = 0; f < 4; ++f) {
          int d = f * 16 + l15;
          bf16x8 vf = *(const bf16x8*)&Vs[cur][d][((kc * 4 + lg) ^ (d & 7)) * 8];
          o[rf][f] = __builtin_amdgcn_mfma_f32_16x16x32_bf16(pf, vf, o[rf][f], 0, 0, 0);
        }
      }
    }

    // ---- land next V into alt buffer, sync ----
    if (s < s_last) {
      scatter_V(cur ^ 1);
      cur ^= 1;
    }
    __syncthreads();
  }

  // ---- finalize ----
  #pragma unroll
  for (int rf = 0; rf < 2; ++rf)
    #pragma unroll
    for (int f = 0; f < 4; ++f)
      #pragma unroll
      for (int r = 0; r < 4; ++r) {
        float v = o[rf][f][r] / l_r[rf][r];
        int row = qb * 128 + w * 32 + rf * 16 + lg * 4 + r;
        out[(size_t)row * C_DIM + h * 64 + f * 16 + l15] = f2b(v);
      }
}

// ---------------------------------------------------------------------------
extern "C" void kernel_launch(void* const* d_in, const int* in_sizes, int n_in,
                              void* d_out, int out_size, void* d_ws, size_t ws_size,
                              hipStream_t stream) {
  const float* x     = (const float*)d_in[0];
  const float* ln1_g = (const float*)d_in[1];
  const float* ln1_b = (const float*)d_in[2];
  const float* w_qkv = (const float*)d_in[3];
  const float* b_qkv = (const float*)d_in[4];
  const float* w_out = (const float*)d_in[5];
  const float* b_out = (const float*)d_in[6];
  const float* ln2_g = (const float*)d_in[7];
  const float* ln2_b = (const float*)d_in[8];
  const float* w_fc1 = (const float*)d_in[9];
  const float* b_fc1 = (const float*)d_in[10];
  const float* w_fc2 = (const float*)d_in[11];
  const float* b_fc2 = (const float*)d_in[12];

  char* ws = (char*)d_ws;
  size_t off = 0;
  auto alloc = [&](size_t bytes) {
    void* p = ws + off;
    off = (off + bytes + 255) & ~(size_t)255;
    return p;
  };
  ushort_t* wqkvT = (ushort_t*)alloc((size_t)3 * C_DIM * C_DIM * 2);
  ushort_t* woutT = (ushort_t*)alloc((size_t)C_DIM * C_DIM * 2);
  ushort_t* wfc1T = (ushort_t*)alloc((size_t)4 * C_DIM * C_DIM * 2);
  ushort_t* wfc2T = (ushort_t*)alloc((size_t)C_DIM * 4 * C_DIM * 2);
  ushort_t* xn1   = (ushort_t*)alloc((size_t)T_SEQ * C_DIM * 2);
  ushort_t* qkv   = (ushort_t*)alloc((size_t)T_SEQ * 3 * C_DIM * 2);
  ushort_t* attnO = (ushort_t*)alloc((size_t)T_SEQ * C_DIM * 2);
  float*    x2    = (float*)   alloc((size_t)T_SEQ * C_DIM * 4);
  ushort_t* xn2   = (ushort_t*)alloc((size_t)T_SEQ * C_DIM * 2);
  ushort_t* hbuf  = (ushort_t*)alloc((size_t)T_SEQ * 4 * C_DIM * 2);
  (void)ws_size;

  cast_transpose<<<dim3(96, 32),  256, 0, stream>>>(w_qkv, wqkvT, C_DIM, 3 * C_DIM);
  cast_transpose<<<dim3(32, 32),  256, 0, stream>>>(w_out, woutT, C_DIM, C_DIM);
  cast_transpose<<<dim3(128, 32), 256, 0, stream>>>(w_fc1, wfc1T, C_DIM, 4 * C_DIM);
  cast_transpose<<<dim3(32, 128), 256, 0, stream>>>(w_fc2, wfc2T, 4 * C_DIM, C_DIM);

  ln_kernel<<<dim3(T_SEQ), 256, 0, stream>>>(x, ln1_g, ln1_b, xn1);

  gemm_bt<false, false, false><<<dim3(24, 32), 256, 0, stream>>>(
      xn1, wqkvT, b_qkv, nullptr, nullptr, qkv, T_SEQ, 3 * C_DIM, C_DIM);

  attn_kernel<<<dim3(T_SEQ / 128, NH), 256, 0, stream>>>(qkv, attnO);

  gemm_bt<false, true, true><<<dim3(8, 32), 256, 0, stream>>>(
      attnO, woutT, b_out, x, x2, nullptr, T_SEQ, C_DIM, C_DIM);

  ln_kernel<<<dim3(T_SEQ), 256, 0, stream>>>(x2, ln2_g, ln2_b, xn2);

  gemm_bt<true, false, false><<<dim3(32, 32), 256, 0, stream>>>(
      xn2, wfc1T, b_fc1, nullptr, nullptr, hbuf, T_SEQ, 4 * C_DIM, C_DIM);

  gemm_bt<false, true, true><<<dim3(8, 32), 256, 0, stream>>>(
      hbuf, wfc2T, b_fc2, x2, (float*)d_out, nullptr, T_SEQ, C_DIM, 4 * C_DIM);
}

// Round 7
// 547.501 us; speedup vs baseline: 1.1626x; 1.1626x over previous
//
#include <hip/hip_runtime.h>
#include <hip/hip_bf16.h>
#include <math.h>

typedef __attribute__((ext_vector_type(8))) short bf16x8;
typedef __attribute__((ext_vector_type(4))) float f32x4;
typedef unsigned short ushort_t;

#define T_SEQ 4096
#define C_DIM 1024
#define NH 16
#define HD 64

__device__ __forceinline__ ushort_t f2b(float f) {
  union { float f; unsigned u; } v; v.f = f;
  unsigned r = v.u + 0x7FFF + ((v.u >> 16) & 1);   // RNE
  return (ushort_t)(r >> 16);
}

// ---------------- cast + transpose: W[K][N] fp32 -> WT[N][K] bf16 -----------
__global__ __launch_bounds__(256) void cast_transpose(const float* __restrict__ W,
                                                      ushort_t* __restrict__ WT,
                                                      int K, int N) {
  __shared__ ushort_t tile[32][40];
  int n0 = blockIdx.x * 32, k0 = blockIdx.y * 32;
  int t = threadIdx.x;
  int kl = t >> 3, nl = (t & 7) * 4;
  float4 v = *(const float4*)(W + (size_t)(k0 + kl) * N + n0 + nl);
  ushort4 c;
  c.x = f2b(v.x); c.y = f2b(v.y); c.z = f2b(v.z); c.w = f2b(v.w);
  *(ushort4*)&tile[kl][nl] = c;
  __syncthreads();
  int nl2 = t >> 3, kl2 = (t & 7) * 4;
  ushort4 o;
  o.x = tile[kl2 + 0][nl2];
  o.y = tile[kl2 + 1][nl2];
  o.z = tile[kl2 + 2][nl2];
  o.w = tile[kl2 + 3][nl2];
  *(ushort4*)(WT + (size_t)(n0 + nl2) * K + k0 + kl2) = o;
}

// ---------------- LayerNorm: fp32 [rows][1024] -> bf16 ----------------------
__global__ __launch_bounds__(256) void ln_kernel(const float* __restrict__ x,
                                                 const float* __restrict__ g,
                                                 const float* __restrict__ b,
                                                 ushort_t* __restrict__ out) {
  int row = blockIdx.x;
  int tid = threadIdx.x;
  float4 v = ((const float4*)(x + (size_t)row * C_DIM))[tid];
  float s  = v.x + v.y + v.z + v.w;
  float sq = v.x*v.x + v.y*v.y + v.z*v.z + v.w*v.w;
  #pragma unroll
  for (int m = 32; m >= 1; m >>= 1) {
    s  += __shfl_down(s, m, 64);
    sq += __shfl_down(sq, m, 64);
  }
  __shared__ float red[8];
  int wid = tid >> 6, lane = tid & 63;
  if (lane == 0) { red[wid] = s; red[wid + 4] = sq; }
  __syncthreads();
  s  = red[0] + red[1] + red[2] + red[3];
  sq = red[4] + red[5] + red[6] + red[7];
  float mu   = s * (1.0f / C_DIM);
  float var  = sq * (1.0f / C_DIM) - mu * mu;
  float rstd = rsqrtf(var + 1e-5f);
  float4 gg = ((const float4*)g)[tid];
  float4 bb = ((const float4*)b)[tid];
  ushort4 o;
  o.x = f2b((v.x - mu) * rstd * gg.x + bb.x);
  o.y = f2b((v.y - mu) * rstd * gg.y + bb.y);
  o.z = f2b((v.z - mu) * rstd * gg.z + bb.z);
  o.w = f2b((v.w - mu) * rstd * gg.w + bb.w);
  ((ushort4*)(out + (size_t)row * C_DIM))[tid] = o;
}

// ---------------- bf16 MFMA GEMM, m97 structure (unchanged) -----------------
template<bool GELU, bool OUT_F32, bool RES>
__global__ __launch_bounds__(256) void gemm_bt(
    const ushort_t* __restrict__ A, const ushort_t* __restrict__ BT,
    const float* __restrict__ bias, const float* __restrict__ res,
    float* __restrict__ outF, ushort_t* __restrict__ outB,
    int M, int N, int K) {
  __shared__ ushort_t As[128][64];
  __shared__ ushort_t Bs[128][64];
  int tid  = threadIdx.x;
  int lane = tid & 63, w = tid >> 6;
  int wr = (w >> 1) * 64, wc = (w & 1) * 64;
  int brow = blockIdx.y * 128, bcol = blockIdx.x * 128;
  int l15 = lane & 15, lg = lane >> 4;

  f32x4 acc[4][4];
  #pragma unroll
  for (int m = 0; m < 4; ++m)
    #pragma unroll
    for (int n = 0; n < 4; ++n)
      acc[m][n] = (f32x4){0.f, 0.f, 0.f, 0.f};

  for (int k0 = 0; k0 < K; k0 += 64) {
    #pragma unroll
    for (int it = 0; it < 4; ++it) {
      int idx = it * 256 + tid;
      int r = idx >> 3, c = (idx & 7) * 8;
      __builtin_amdgcn_global_load_lds(
          (const __attribute__((address_space(1))) unsigned*)(A + (size_t)(brow + r) * K + k0 + c),
          (__attribute__((address_space(3))) unsigned*)&As[0][0] + idx * 4,
          16, 0, 0);
    }
    #pragma unroll
    for (int it = 0; it < 4; ++it) {
      int idx = it * 256 + tid;
      int r = idx >> 3, c = (idx & 7) * 8;
      __builtin_amdgcn_global_load_lds(
          (const __attribute__((address_space(1))) unsigned*)(BT + (size_t)(bcol + r) * K + k0 + c),
          (__attribute__((address_space(3))) unsigned*)&Bs[0][0] + idx * 4,
          16, 0, 0);
    }
    __syncthreads();
    #pragma unroll
    for (int half = 0; half < 2; ++half) {
      bf16x8 af[4], bfr[4];
      #pragma unroll
      for (int m = 0; m < 4; ++m)
        af[m] = *(const bf16x8*)&As[wr + m * 16 + l15][half * 32 + lg * 8];
      #pragma unroll
      for (int n = 0; n < 4; ++n)
        bfr[n] = *(const bf16x8*)&Bs[wc + n * 16 + l15][half * 32 + lg * 8];
      #pragma unroll
      for (int m = 0; m < 4; ++m)
        #pragma unroll
        for (int n = 0; n < 4; ++n)
          acc[m][n] = __builtin_amdgcn_mfma_f32_16x16x32_bf16(af[m], bfr[n], acc[m][n], 0, 0, 0);
    }
    __syncthreads();
  }

  #pragma unroll
  for (int m = 0; m < 4; ++m) {
    int row0 = brow + wr + m * 16 + lg * 4;
    #pragma unroll
    for (int n = 0; n < 4; ++n) {
      int col = bcol + wc + n * 16 + l15;
      float bv = bias[col];
      #pragma unroll
      for (int r = 0; r < 4; ++r) {
        int row = row0 + r;
        float v = acc[m][n][r] + bv;
        if (RES)  v += res[(size_t)row * N + col];
        if (GELU) v = 0.5f * v * (1.0f + erff(v * 0.70710678118f));
        if (OUT_F32) outF[(size_t)row * N + col] = v;
        else         outB[(size_t)row * N + col] = f2b(v);
      }
    }
  }
}

// ---------------- causal flash attention, split-KV chunks -------------------
// Round-5-verified inner tile code (KVBLK=128, swizzled K/V, wave-private Pb).
// Each block = (chunk c, head h): q-tile qb, KV iterations [it0, it0+itn).
// Chunk map (160 chunks): qb<16:1 split, <32:2, <48:3, <64:4  => <=9 iters/block.
// Writes partial (O_unnorm f32 [64][64], m[64], l[64]); merge kernel combines.
__global__ __launch_bounds__(256) void attn_kernel(const ushort_t* __restrict__ qkv,
                                                   float* __restrict__ part_O,
                                                   float* __restrict__ part_ml) {
  __shared__ ushort_t Ks[128][64];
  __shared__ ushort_t Vs[64][128];
  __shared__ ushort_t Pb[4][16][136];
  int h = blockIdx.y;
  int c = blockIdx.x;                    // 0..159
  int qb, split, nsplit;
  if (c < 16)      { qb = c;                split = 0;           nsplit = 1; }
  else if (c < 48) { qb = 16 + ((c - 16) >> 1); split = (c - 16) & 1; nsplit = 2; }
  else if (c < 96) { qb = 32 + (c - 48) / 3;    split = (c - 48) % 3; nsplit = 3; }
  else             { qb = 48 + ((c - 96) >> 2); split = (c - 96) & 3; nsplit = 4; }
  int niter = (qb >> 1) + 1;
  int qd = niter / nsplit, rem = niter % nsplit;
  int it0 = split * qd + (split < rem ? split : rem);
  int itn = qd + (split < rem ? 1 : 0);

  int tid = threadIdx.x, lane = tid & 63, w = tid >> 6;
  int l15 = lane & 15, lg = lane >> 4;

  bf16x8 qf[2];
  {
    int qrow = qb * 64 + w * 16 + l15;
    const ushort_t* qp = qkv + (size_t)qrow * 3072 + h * 64;
    qf[0] = *(const bf16x8*)(qp + lg * 8);
    qf[1] = *(const bf16x8*)(qp + 32 + lg * 8);
  }
  float m_r[4], l_r[4];
  f32x4 o[4];
  #pragma unroll
  for (int r = 0; r < 4; ++r) { m_r[r] = -1e30f; l_r[r] = 0.f; }
  #pragma unroll
  for (int f = 0; f < 4; ++f) o[f] = (f32x4){0.f, 0.f, 0.f, 0.f};

  for (int s = it0; s < it0 + itn; ++s) {
    const ushort_t* kbase = qkv + (size_t)(s * 128) * 3072 + h * 64 + 1024;
    const ushort_t* vbase = kbase + 1024;
    #pragma unroll
    for (int it = 0; it < 4; ++it) {
      int idx = it * 256 + tid;            // 128 rows x 8 chunks
      int r = idx >> 3, ch = idx & 7;
      int srcc = (ch ^ (r & 7)) * 8;
      __builtin_amdgcn_global_load_lds(
          (const __attribute__((address_space(1))) unsigned*)(kbase + (size_t)r * 3072 + srcc),
          (__attribute__((address_space(3))) unsigned*)&Ks[0][0] + idx * 4,
          16, 0, 0);
    }
    #pragma unroll
    for (int it = 0; it < 4; ++it) {
      int idx = it * 256 + tid;
      int kv = (idx & 63) | ((idx >> 9) << 6);
      int d0 = ((idx >> 6) & 7) * 8;
      bf16x8 vv = *(const bf16x8*)(vbase + (size_t)kv * 3072 + d0);
      #pragma unroll
      for (int e = 0; e < 8; ++e)
        Vs[d0 + e][kv ^ (e << 3)] = ((ushort_t*)&vv)[e];
    }
    __syncthreads();

    // ---- S = Q K^T : 8 col-frags of 16 ----
    f32x4 sf[8];
    #pragma unroll
    for (int f = 0; f < 8; ++f) {
      int row = f * 16 + l15;
      bf16x8 k0 = *(const bf16x8*)&Ks[row][(lg ^ (row & 7)) * 8];
      bf16x8 k1 = *(const bf16x8*)&Ks[row][((4 + lg) ^ (row & 7)) * 8];
      f32x4 a = (f32x4){0.f, 0.f, 0.f, 0.f};
      a = __builtin_amdgcn_mfma_f32_16x16x32_bf16(qf[0], k0, a, 0, 0, 0);
      a = __builtin_amdgcn_mfma_f32_16x16x32_bf16(qf[1], k1, a, 0, 0, 0);
      sf[f] = a;
    }

    float p[8][4];
    #pragma unroll
    for (int f = 0; f < 8; ++f)
      #pragma unroll
      for (int r = 0; r < 4; ++r) {
        float v = sf[f][r] * 0.125f;
        if (s == niter - 1) {
          int rl = qb * 64 + w * 16 + lg * 4 + r;
          int cl = s * 128 + f * 16 + l15;
          if (cl > rl) v = -1e30f;
        }
        p[f][r] = v;
      }

    #pragma unroll
    for (int r = 0; r < 4; ++r) {
      float mx = p[0][r];
      #pragma unroll
      for (int f = 1; f < 8; ++f) mx = fmaxf(mx, p[f][r]);
      #pragma unroll
      for (int off = 1; off < 16; off <<= 1) mx = fmaxf(mx, __shfl_xor(mx, off, 64));
      float mn = fmaxf(m_r[r], mx);
      float sc = __expf(m_r[r] - mn);
      float sum = 0.f;
      #pragma unroll
      for (int f = 0; f < 8; ++f) { p[f][r] = __expf(p[f][r] - mn); sum += p[f][r]; }
      #pragma unroll
      for (int off = 1; off < 16; off <<= 1) sum += __shfl_xor(sum, off, 64);
      l_r[r] = l_r[r] * sc + sum;
      m_r[r] = mn;
      #pragma unroll
      for (int f = 0; f < 4; ++f) o[f][r] *= sc;
    }

    #pragma unroll
    for (int f = 0; f < 8; ++f)
      #pragma unroll
      for (int r = 0; r < 4; ++r)
        Pb[w][lg * 4 + r][f * 16 + l15] = f2b(p[f][r]);

    #pragma unroll
    for (int kc = 0; kc < 4; ++kc) {
      bf16x8 pf = *(const bf16x8*)&Pb[w][l15][kc * 32 + lg * 8];
      #pragma unroll
      for (int f = 0; f < 4; ++f) {
        int d = f * 16 + l15;
        bf16x8 vf = *(const bf16x8*)&Vs[d][(((kc * 4) + lg) ^ (d & 7)) * 8];
        o[f] = __builtin_amdgcn_mfma_f32_16x16x32_bf16(pf, vf, o[f], 0, 0, 0);
      }
    }
    __syncthreads();
  }

  // ---- write partials (unnormalized) ----
  int pidx = h * 160 + c;
  float* po = part_O + (size_t)pidx * 4096;
  #pragma unroll
  for (int f = 0; f < 4; ++f)
    #pragma unroll
    for (int r = 0; r < 4; ++r)
      po[(w * 16 + lg * 4 + r) * 64 + f * 16 + l15] = o[f][r];
  if (l15 == 0) {
    float* pm = part_ml + (size_t)pidx * 128;
    #pragma unroll
    for (int r = 0; r < 4; ++r) {
      int row = w * 16 + lg * 4 + r;
      pm[row]      = m_r[r];
      pm[64 + row] = l_r[r];
    }
  }
}

// ---------------- merge partials -> bf16 attn output ------------------------
__global__ __launch_bounds__(256) void attn_merge(const float* __restrict__ part_O,
                                                  const float* __restrict__ part_ml,
                                                  ushort_t* __restrict__ out) {
  int qb = blockIdx.x, h = blockIdx.y;
  int nsplit, base;
  if (qb < 16)      { nsplit = 1; base = qb; }
  else if (qb < 32) { nsplit = 2; base = 16 + 2 * (qb - 16); }
  else if (qb < 48) { nsplit = 3; base = 48 + 3 * (qb - 32); }
  else              { nsplit = 4; base = 96 + 4 * (qb - 48); }
  int t = threadIdx.x;
  int r = t >> 2, d0 = (t & 3) * 16;
  int p0 = h * 160 + base;

  float mv0 = part_ml[(size_t)p0 * 128 + r];
  float lv0 = part_ml[(size_t)p0 * 128 + 64 + r];
  float mv1 = nsplit > 1 ? part_ml[(size_t)(p0 + 1) * 128 + r]      : -1e30f;
  float lv1 = nsplit > 1 ? part_ml[(size_t)(p0 + 1) * 128 + 64 + r] : 0.f;
  float mv2 = nsplit > 2 ? part_ml[(size_t)(p0 + 2) * 128 + r]      : -1e30f;
  float lv2 = nsplit > 2 ? part_ml[(size_t)(p0 + 2) * 128 + 64 + r] : 0.f;
  float mv3 = nsplit > 3 ? part_ml[(size_t)(p0 + 3) * 128 + r]      : -1e30f;
  float lv3 = nsplit > 3 ? part_ml[(size_t)(p0 + 3) * 128 + 64 + r] : 0.f;
  float M = fmaxf(fmaxf(mv0, mv1), fmaxf(mv2, mv3));
  float s0 = __expf(mv0 - M), s1 = __expf(mv1 - M);
  float s2 = __expf(mv2 - M), s3 = __expf(mv3 - M);
  float L = lv0 * s0 + lv1 * s1 + lv2 * s2 + lv3 * s3;
  float inv = 1.0f / L;

  float acc[16];
  #pragma unroll
  for (int e = 0; e < 16; ++e) acc[e] = 0.f;
  {
    const float* po = part_O + (size_t)p0 * 4096 + r * 64 + d0;
    #pragma unroll
    for (int e = 0; e < 16; e += 4) {
      float4 v = *(const float4*)(po + e);
      acc[e] += v.x * s0; acc[e+1] += v.y * s0; acc[e+2] += v.z * s0; acc[e+3] += v.w * s0;
    }
  }
  if (nsplit > 1) {
    const float* po = part_O + (size_t)(p0 + 1) * 4096 + r * 64 + d0;
    #pragma unroll
    for (int e = 0; e < 16; e += 4) {
      float4 v = *(const float4*)(po + e);
      acc[e] += v.x * s1; acc[e+1] += v.y * s1; acc[e+2] += v.z * s1; acc[e+3] += v.w * s1;
    }
  }
  if (nsplit > 2) {
    const float* po = part_O + (size_t)(p0 + 2) * 4096 + r * 64 + d0;
    #pragma unroll
    for (int e = 0; e < 16; e += 4) {
      float4 v = *(const float4*)(po + e);
      acc[e] += v.x * s2; acc[e+1] += v.y * s2; acc[e+2] += v.z * s2; acc[e+3] += v.w * s2;
    }
  }
  if (nsplit > 3) {
    const float* po = part_O + (size_t)(p0 + 3) * 4096 + r * 64 + d0;
    #pragma unroll
    for (int e = 0; e < 16; e += 4) {
      float4 v = *(const float4*)(po + e);
      acc[e] += v.x * s3; acc[e+1] += v.y * s3; acc[e+2] += v.z * s3; acc[e+3] += v.w * s3;
    }
  }

  ushort_t* op = out + (size_t)(qb * 64 + r) * C_DIM + h * 64 + d0;
  #pragma unroll
  for (int e = 0; e < 16; ++e) op[e] = f2b(acc[e] * inv);
}

// ---------------------------------------------------------------------------
extern "C" void kernel_launch(void* const* d_in, const int* in_sizes, int n_in,
                              void* d_out, int out_size, void* d_ws, size_t ws_size,
                              hipStream_t stream) {
  const float* x     = (const float*)d_in[0];
  const float* ln1_g = (const float*)d_in[1];
  const float* ln1_b = (const float*)d_in[2];
  const float* w_qkv = (const float*)d_in[3];
  const float* b_qkv = (const float*)d_in[4];
  const float* w_out = (const float*)d_in[5];
  const float* b_out = (const float*)d_in[6];
  const float* ln2_g = (const float*)d_in[7];
  const float* ln2_b = (const float*)d_in[8];
  const float* w_fc1 = (const float*)d_in[9];
  const float* b_fc1 = (const float*)d_in[10];
  const float* w_fc2 = (const float*)d_in[11];
  const float* b_fc2 = (const float*)d_in[12];

  char* ws = (char*)d_ws;
  size_t off = 0;
  auto alloc = [&](size_t bytes) {
    void* p = ws + off;
    off = (off + bytes + 255) & ~(size_t)255;
    return p;
  };
  ushort_t* wqkvT = (ushort_t*)alloc((size_t)3 * C_DIM * C_DIM * 2);
  ushort_t* woutT = (ushort_t*)alloc((size_t)C_DIM * C_DIM * 2);
  ushort_t* wfc1T = (ushort_t*)alloc((size_t)4 * C_DIM * C_DIM * 2);
  ushort_t* wfc2T = (ushort_t*)alloc((size_t)C_DIM * 4 * C_DIM * 2);
  ushort_t* xn1   = (ushort_t*)alloc((size_t)T_SEQ * C_DIM * 2);
  ushort_t* qkv   = (ushort_t*)alloc((size_t)T_SEQ * 3 * C_DIM * 2);
  ushort_t* attnO = (ushort_t*)alloc((size_t)T_SEQ * C_DIM * 2);
  float*    x2    = (float*)   alloc((size_t)T_SEQ * C_DIM * 4);
  ushort_t* xn2   = (ushort_t*)alloc((size_t)T_SEQ * C_DIM * 2);
  ushort_t* hbuf  = (ushort_t*)alloc((size_t)T_SEQ * 4 * C_DIM * 2);
  (void)ws_size;
  // attention partials alias the x2/xn2/hbuf region (56 MB; written only
  // AFTER attention+merge complete). part_O 41.9 MB + part_ml 1.3 MB.
  float* part_O  = (float*)x2;
  float* part_ml = (float*)((char*)x2 + (size_t)2560 * 4096 * 4);

  cast_transpose<<<dim3(96, 32),  256, 0, stream>>>(w_qkv, wqkvT, C_DIM, 3 * C_DIM);
  cast_transpose<<<dim3(32, 32),  256, 0, stream>>>(w_out, woutT, C_DIM, C_DIM);
  cast_transpose<<<dim3(128, 32), 256, 0, stream>>>(w_fc1, wfc1T, C_DIM, 4 * C_DIM);
  cast_transpose<<<dim3(32, 128), 256, 0, stream>>>(w_fc2, wfc2T, 4 * C_DIM, C_DIM);

  ln_kernel<<<dim3(T_SEQ), 256, 0, stream>>>(x, ln1_g, ln1_b, xn1);

  gemm_bt<false, false, false><<<dim3(24, 32), 256, 0, stream>>>(
      xn1, wqkvT, b_qkv, nullptr, nullptr, qkv, T_SEQ, 3 * C_DIM, C_DIM);

  attn_kernel<<<dim3(160, NH), 256, 0, stream>>>(qkv, part_O, part_ml);
  attn_merge<<<dim3(T_SEQ / 64, NH), 256, 0, stream>>>(part_O, part_ml, attnO);

  gemm_bt<false, true, true><<<dim3(8, 32), 256, 0, stream>>>(
      attnO, woutT, b_out, x, x2, nullptr, T_SEQ, C_DIM, C_DIM);

  ln_kernel<<<dim3(T_SEQ), 256, 0, stream>>>(x2, ln2_g, ln2_b, xn2);

  gemm_bt<true, false, false><<<dim3(32, 32), 256, 0, stream>>>(
      xn2, wfc1T, b_fc1, nullptr, nullptr, hbuf, T_SEQ, 4 * C_DIM, C_DIM);

  gemm_bt<false, true, true><<<dim3(8, 32), 256, 0, stream>>>(
      hbuf, wfc2T, b_fc2, x2, (float*)d_out, nullptr, T_SEQ, C_DIM, 4 * C_DIM);
}

// Round 8
// 478.179 us; speedup vs baseline: 1.3311x; 1.1450x over previous
//
#include <hip/hip_runtime.h>
#include <hip/hip_bf16.h>
#include <math.h>

typedef __attribute__((ext_vector_type(8))) short bf16x8;
typedef __attribute__((ext_vector_type(4))) float f32x4;
typedef unsigned short ushort_t;

#define T_SEQ 4096
#define C_DIM 1024
#define NH 16
#define HD 64

__device__ __forceinline__ ushort_t f2b(float f) {
  union { float f; unsigned u; } v; v.f = f;
  unsigned r = v.u + 0x7FFF + ((v.u >> 16) & 1);   // RNE
  return (ushort_t)(r >> 16);
}

// ---------------- cast + transpose: W[K][N] fp32 -> WT[N][K] bf16 -----------
__global__ __launch_bounds__(256) void cast_transpose(const float* __restrict__ W,
                                                      ushort_t* __restrict__ WT,
                                                      int K, int N) {
  __shared__ ushort_t tile[32][40];
  int n0 = blockIdx.x * 32, k0 = blockIdx.y * 32;
  int t = threadIdx.x;
  int kl = t >> 3, nl = (t & 7) * 4;
  float4 v = *(const float4*)(W + (size_t)(k0 + kl) * N + n0 + nl);
  ushort4 c;
  c.x = f2b(v.x); c.y = f2b(v.y); c.z = f2b(v.z); c.w = f2b(v.w);
  *(ushort4*)&tile[kl][nl] = c;
  __syncthreads();
  int nl2 = t >> 3, kl2 = (t & 7) * 4;
  ushort4 o;
  o.x = tile[kl2 + 0][nl2];
  o.y = tile[kl2 + 1][nl2];
  o.z = tile[kl2 + 2][nl2];
  o.w = tile[kl2 + 3][nl2];
  *(ushort4*)(WT + (size_t)(n0 + nl2) * K + k0 + kl2) = o;
}

// ---------------- LayerNorm: fp32 [rows][1024] -> bf16 ----------------------
__global__ __launch_bounds__(256) void ln_kernel(const float* __restrict__ x,
                                                 const float* __restrict__ g,
                                                 const float* __restrict__ b,
                                                 ushort_t* __restrict__ out) {
  int row = blockIdx.x;
  int tid = threadIdx.x;
  float4 v = ((const float4*)(x + (size_t)row * C_DIM))[tid];
  float s  = v.x + v.y + v.z + v.w;
  float sq = v.x*v.x + v.y*v.y + v.z*v.z + v.w*v.w;
  #pragma unroll
  for (int m = 32; m >= 1; m >>= 1) {
    s  += __shfl_down(s, m, 64);
    sq += __shfl_down(sq, m, 64);
  }
  __shared__ float red[8];
  int wid = tid >> 6, lane = tid & 63;
  if (lane == 0) { red[wid] = s; red[wid + 4] = sq; }
  __syncthreads();
  s  = red[0] + red[1] + red[2] + red[3];
  sq = red[4] + red[5] + red[6] + red[7];
  float mu   = s * (1.0f / C_DIM);
  float var  = sq * (1.0f / C_DIM) - mu * mu;
  float rstd = rsqrtf(var + 1e-5f);
  float4 gg = ((const float4*)g)[tid];
  float4 bb = ((const float4*)b)[tid];
  ushort4 o;
  o.x = f2b((v.x - mu) * rstd * gg.x + bb.x);
  o.y = f2b((v.y - mu) * rstd * gg.y + bb.y);
  o.z = f2b((v.z - mu) * rstd * gg.z + bb.z);
  o.w = f2b((v.w - mu) * rstd * gg.w + bb.w);
  ((ushort4*)(out + (size_t)row * C_DIM))[tid] = o;
}

// ---------------- bf16 MFMA GEMM, 2-phase double-buffered (BK=32) -----------
// C = A[M,K] @ BT[N,K]^T + bias (+res) (+gelu)
// 128x128 tile, 256 thr = 4 waves (2x2), wave = 64x64 = 4x4 frags.
// Both tiles via global_load_lds width-16; next K-tile's loads issued BEFORE
// computing current (single barrier/iter drains them after compute overlap).
template<bool GELU, bool OUT_F32, bool RES>
__global__ __launch_bounds__(256) void gemm_bt(
    const ushort_t* __restrict__ A, const ushort_t* __restrict__ BT,
    const float* __restrict__ bias, const float* __restrict__ res,
    float* __restrict__ outF, ushort_t* __restrict__ outB,
    int M, int N, int K) {
  __shared__ ushort_t As[2][128][32];
  __shared__ ushort_t Bs[2][128][32];
  int tid  = threadIdx.x;
  int lane = tid & 63, w = tid >> 6;
  int wr = (w >> 1) * 64, wc = (w & 1) * 64;
  int brow = blockIdx.y * 128, bcol = blockIdx.x * 128;
  int l15 = lane & 15, lg = lane >> 4;

  f32x4 acc[4][4];
  #pragma unroll
  for (int m = 0; m < 4; ++m)
    #pragma unroll
    for (int n = 0; n < 4; ++n)
      acc[m][n] = (f32x4){0.f, 0.f, 0.f, 0.f};

  auto stage = [&](int buf, int k0) {
    #pragma unroll
    for (int it = 0; it < 2; ++it) {
      int idx = it * 256 + tid;            // 0..511: 128 rows x 4 chunks
      int r = idx >> 2, c = (idx & 3) * 8;
      __builtin_amdgcn_global_load_lds(
          (const __attribute__((address_space(1))) unsigned*)(A + (size_t)(brow + r) * K + k0 + c),
          (__attribute__((address_space(3))) unsigned*)&As[buf][0][0] + idx * 4,
          16, 0, 0);
    }
    #pragma unroll
    for (int it = 0; it < 2; ++it) {
      int idx = it * 256 + tid;
      int r = idx >> 2, c = (idx & 3) * 8;
      __builtin_amdgcn_global_load_lds(
          (const __attribute__((address_space(1))) unsigned*)(BT + (size_t)(bcol + r) * K + k0 + c),
          (__attribute__((address_space(3))) unsigned*)&Bs[buf][0][0] + idx * 4,
          16, 0, 0);
    }
  };

  int nt = K >> 5;
  stage(0, 0);
  __syncthreads();
  for (int t = 0; t < nt; ++t) {
    if (t + 1 < nt) stage((t + 1) & 1, (t + 1) << 5);
    int cur = t & 1;
    bf16x8 af[4], bfr[4];
    #pragma unroll
    for (int m = 0; m < 4; ++m)
      af[m] = *(const bf16x8*)&As[cur][wr + m * 16 + l15][lg * 8];
    #pragma unroll
    for (int n = 0; n < 4; ++n)
      bfr[n] = *(const bf16x8*)&Bs[cur][wc + n * 16 + l15][lg * 8];
    #pragma unroll
    for (int m = 0; m < 4; ++m)
      #pragma unroll
      for (int n = 0; n < 4; ++n)
        acc[m][n] = __builtin_amdgcn_mfma_f32_16x16x32_bf16(af[m], bfr[n], acc[m][n], 0, 0, 0);
    __syncthreads();
  }

  #pragma unroll
  for (int m = 0; m < 4; ++m) {
    int row0 = brow + wr + m * 16 + lg * 4;
    #pragma unroll
    for (int n = 0; n < 4; ++n) {
      int col = bcol + wc + n * 16 + l15;
      float bv = bias[col];
      #pragma unroll
      for (int r = 0; r < 4; ++r) {
        int row = row0 + r;
        float v = acc[m][n][r] + bv;
        if (RES)  v += res[(size_t)row * N + col];
        if (GELU) v = 0.5f * v * (1.0f + erff(v * 0.70710678118f));
        if (OUT_F32) outF[(size_t)row * N + col] = v;
        else         outB[(size_t)row * N + col] = f2b(v);
      }
    }
  }
}

// ---------------- causal flash attention, split-KV + swapped QK^T -----------
// S^T = mfma(K,Q): lane holds P[kv=f*16+lg*4+r][q=l15] -> softmax row is
// lane-local over 32 regs + 2 shuffles (xor 16/32). P packed via
// v_cvt_pk_bf16_f32 pairs (kv-consecutive in r) -> 16 ds_write_b32.
__global__ __launch_bounds__(256) void attn_kernel(const ushort_t* __restrict__ qkv,
                                                   float* __restrict__ part_O,
                                                   float* __restrict__ part_ml) {
  __shared__ ushort_t Ks[128][64];
  __shared__ ushort_t Vs[64][128];
  __shared__ ushort_t Pb[4][16][136];
  int h = blockIdx.y;
  int c = blockIdx.x;                    // 0..159
  int qb, split, nsplit;
  if (c < 16)      { qb = c;                split = 0;           nsplit = 1; }
  else if (c < 48) { qb = 16 + ((c - 16) >> 1); split = (c - 16) & 1; nsplit = 2; }
  else if (c < 96) { qb = 32 + (c - 48) / 3;    split = (c - 48) % 3; nsplit = 3; }
  else             { qb = 48 + ((c - 96) >> 2); split = (c - 96) & 3; nsplit = 4; }
  int niter = (qb >> 1) + 1;
  int qd = niter / nsplit, rem = niter % nsplit;
  int it0 = split * qd + (split < rem ? split : rem);
  int itn = qd + (split < rem ? 1 : 0);

  int tid = threadIdx.x, lane = tid & 63, w = tid >> 6;
  int l15 = lane & 15, lg = lane >> 4;

  bf16x8 qf[2];
  {
    int qrow = qb * 64 + w * 16 + l15;
    const ushort_t* qp = qkv + (size_t)qrow * 3072 + h * 64;
    qf[0] = *(const bf16x8*)(qp + lg * 8);
    qf[1] = *(const bf16x8*)(qp + 32 + lg * 8);
  }
  float m_l = -1e30f, l_l = 0.f;        // per-lane: q-row = w*16 + l15
  f32x4 o[4];                            // O[q=lg*4+r][d=f*16+l15]
  #pragma unroll
  for (int f = 0; f < 4; ++f) o[f] = (f32x4){0.f, 0.f, 0.f, 0.f};

  for (int s = it0; s < it0 + itn; ++s) {
    const ushort_t* kbase = qkv + (size_t)(s * 128) * 3072 + h * 64 + 1024;
    const ushort_t* vbase = kbase + 1024;
    #pragma unroll
    for (int it = 0; it < 4; ++it) {
      int idx = it * 256 + tid;            // 128 rows x 8 chunks
      int r = idx >> 3, ch = idx & 7;
      int srcc = (ch ^ (r & 7)) * 8;
      __builtin_amdgcn_global_load_lds(
          (const __attribute__((address_space(1))) unsigned*)(kbase + (size_t)r * 3072 + srcc),
          (__attribute__((address_space(3))) unsigned*)&Ks[0][0] + idx * 4,
          16, 0, 0);
    }
    #pragma unroll
    for (int it = 0; it < 4; ++it) {
      int idx = it * 256 + tid;
      int kv = (idx & 63) | ((idx >> 9) << 6);
      int d0 = ((idx >> 6) & 7) * 8;
      bf16x8 vv = *(const bf16x8*)(vbase + (size_t)kv * 3072 + d0);
      #pragma unroll
      for (int e = 0; e < 8; ++e)
        Vs[d0 + e][kv ^ (e << 3)] = ((ushort_t*)&vv)[e];
    }
    __syncthreads();

    // ---- S^T = K Q^T : p[f][r] = S[kv = s*128+f*16+lg*4+r][q = w*16+l15] ----
    float p[8][4];
    #pragma unroll
    for (int f = 0; f < 8; ++f) {
      int kvrow = f * 16 + l15;
      bf16x8 k0 = *(const bf16x8*)&Ks[kvrow][(lg ^ (kvrow & 7)) * 8];
      bf16x8 k1 = *(const bf16x8*)&Ks[kvrow][((4 + lg) ^ (kvrow & 7)) * 8];
      f32x4 a = (f32x4){0.f, 0.f, 0.f, 0.f};
      a = __builtin_amdgcn_mfma_f32_16x16x32_bf16(k0, qf[0], a, 0, 0, 0);
      a = __builtin_amdgcn_mfma_f32_16x16x32_bf16(k1, qf[1], a, 0, 0, 0);
      #pragma unroll
      for (int r = 0; r < 4; ++r) {
        float v = a[r] * 0.125f;
        if (s == niter - 1) {
          int cl = s * 128 + f * 16 + lg * 4 + r;   // kv
          int rl = qb * 64 + w * 16 + l15;          // q
          if (cl > rl) v = -1e30f;
        }
        p[f][r] = v;
      }
    }

    // ---- lane-local online softmax (row = l15's q-row) ----
    float mx = p[0][0];
    #pragma unroll
    for (int f = 0; f < 8; ++f)
      #pragma unroll
      for (int r = 0; r < 4; ++r) mx = fmaxf(mx, p[f][r]);
    mx = fmaxf(mx, __shfl_xor(mx, 16, 64));
    mx = fmaxf(mx, __shfl_xor(mx, 32, 64));
    float mn = fmaxf(m_l, mx);
    float sc = __expf(m_l - mn);
    m_l = mn;
    float sum = 0.f;
    #pragma unroll
    for (int f = 0; f < 8; ++f)
      #pragma unroll
      for (int r = 0; r < 4; ++r) { p[f][r] = __expf(p[f][r] - mn); sum += p[f][r]; }
    sum += __shfl_xor(sum, 16, 64);
    sum += __shfl_xor(sum, 32, 64);
    l_l = l_l * sc + sum;

    // ---- rescale O (rows lg*4+r need sc of lane lg*4+r) ----
    #pragma unroll
    for (int r = 0; r < 4; ++r) {
      float scr = __shfl(sc, lg * 4 + r, 64);
      #pragma unroll
      for (int f = 0; f < 4; ++f) o[f][r] *= scr;
    }

    // ---- P -> LDS: pack kv-consecutive pairs with v_cvt_pk_bf16_f32 ----
    #pragma unroll
    for (int f = 0; f < 8; ++f) {
      #pragma unroll
      for (int rp = 0; rp < 2; ++rp) {
        unsigned u;
        asm("v_cvt_pk_bf16_f32 %0, %1, %2" : "=v"(u) : "v"(p[f][2 * rp]), "v"(p[f][2 * rp + 1]));
        *(unsigned*)&Pb[w][l15][f * 16 + lg * 4 + 2 * rp] = u;
      }
    }

    // ---- O += P V  (k = 128 in 4 chunks of 32) ----
    #pragma unroll
    for (int kc = 0; kc < 4; ++kc) {
      bf16x8 pf = *(const bf16x8*)&Pb[w][l15][kc * 32 + lg * 8];
      #pragma unroll
      for (int f = 0; f < 4; ++f) {
        int d = f * 16 + l15;
        bf16x8 vf = *(const bf16x8*)&Vs[d][(((kc * 4) + lg) ^ (d & 7)) * 8];
        o[f] = __builtin_amdgcn_mfma_f32_16x16x32_bf16(pf, vf, o[f], 0, 0, 0);
      }
    }
    __syncthreads();
  }

  // ---- write partials (unnormalized) ----
  int pidx = h * 160 + c;
  float* po = part_O + (size_t)pidx * 4096;
  #pragma unroll
  for (int f = 0; f < 4; ++f)
    #pragma unroll
    for (int r = 0; r < 4; ++r)
      po[(w * 16 + lg * 4 + r) * 64 + f * 16 + l15] = o[f][r];
  if (lane < 16) {
    float* pm = part_ml + (size_t)pidx * 128;
    pm[w * 16 + lane]      = m_l;
    pm[64 + w * 16 + lane] = l_l;
  }
}

// ---------------- merge partials -> bf16 attn output ------------------------
__global__ __launch_bounds__(256) void attn_merge(const float* __restrict__ part_O,
                                                  const float* __restrict__ part_ml,
                                                  ushort_t* __restrict__ out) {
  int qb = blockIdx.x, h = blockIdx.y;
  int nsplit, base;
  if (qb < 16)      { nsplit = 1; base = qb; }
  else if (qb < 32) { nsplit = 2; base = 16 + 2 * (qb - 16); }
  else if (qb < 48) { nsplit = 3; base = 48 + 3 * (qb - 32); }
  else              { nsplit = 4; base = 96 + 4 * (qb - 48); }
  int t = threadIdx.x;
  int r = t >> 2, d0 = (t & 3) * 16;
  int p0 = h * 160 + base;

  float mv0 = part_ml[(size_t)p0 * 128 + r];
  float lv0 = part_ml[(size_t)p0 * 128 + 64 + r];
  float mv1 = nsplit > 1 ? part_ml[(size_t)(p0 + 1) * 128 + r]      : -1e30f;
  float lv1 = nsplit > 1 ? part_ml[(size_t)(p0 + 1) * 128 + 64 + r] : 0.f;
  float mv2 = nsplit > 2 ? part_ml[(size_t)(p0 + 2) * 128 + r]      : -1e30f;
  float lv2 = nsplit > 2 ? part_ml[(size_t)(p0 + 2) * 128 + 64 + r] : 0.f;
  float mv3 = nsplit > 3 ? part_ml[(size_t)(p0 + 3) * 128 + r]      : -1e30f;
  float lv3 = nsplit > 3 ? part_ml[(size_t)(p0 + 3) * 128 + 64 + r] : 0.f;
  float M = fmaxf(fmaxf(mv0, mv1), fmaxf(mv2, mv3));
  float s0 = __expf(mv0 - M), s1 = __expf(mv1 - M);
  float s2 = __expf(mv2 - M), s3 = __expf(mv3 - M);
  float L = lv0 * s0 + lv1 * s1 + lv2 * s2 + lv3 * s3;
  float inv = 1.0f / L;

  float acc[16];
  #pragma unroll
  for (int e = 0; e < 16; ++e) acc[e] = 0.f;
  {
    const float* po = part_O + (size_t)p0 * 4096 + r * 64 + d0;
    #pragma unroll
    for (int e = 0; e < 16; e += 4) {
      float4 v = *(const float4*)(po + e);
      acc[e] += v.x * s0; acc[e+1] += v.y * s0; acc[e+2] += v.z * s0; acc[e+3] += v.w * s0;
    }
  }
  if (nsplit > 1) {
    const float* po = part_O + (size_t)(p0 + 1) * 4096 + r * 64 + d0;
    #pragma unroll
    for (int e = 0; e < 16; e += 4) {
      float4 v = *(const float4*)(po + e);
      acc[e] += v.x * s1; acc[e+1] += v.y * s1; acc[e+2] += v.z * s1; acc[e+3] += v.w * s1;
    }
  }
  if (nsplit > 2) {
    const float* po = part_O + (size_t)(p0 + 2) * 4096 + r * 64 + d0;
    #pragma unroll
    for (int e = 0; e < 16; e += 4) {
      float4 v = *(const float4*)(po + e);
      acc[e] += v.x * s2; acc[e+1] += v.y * s2; acc[e+2] += v.z * s2; acc[e+3] += v.w * s2;
    }
  }
  if (nsplit > 3) {
    const float* po = part_O + (size_t)(p0 + 3) * 4096 + r * 64 + d0;
    #pragma unroll
    for (int e = 0; e < 16; e += 4) {
      float4 v = *(const float4*)(po + e);
      acc[e] += v.x * s3; acc[e+1] += v.y * s3; acc[e+2] += v.z * s3; acc[e+3] += v.w * s3;
    }
  }

  ushort_t* op = out + (size_t)(qb * 64 + r) * C_DIM + h * 64 + d0;
  #pragma unroll
  for (int e = 0; e < 16; ++e) op[e] = f2b(acc[e] * inv);
}

// ---------------------------------------------------------------------------
extern "C" void kernel_launch(void* const* d_in, const int* in_sizes, int n_in,
                              void* d_out, int out_size, void* d_ws, size_t ws_size,
                              hipStream_t stream) {
  const float* x     = (const float*)d_in[0];
  const float* ln1_g = (const float*)d_in[1];
  const float* ln1_b = (const float*)d_in[2];
  const float* w_qkv = (const float*)d_in[3];
  const float* b_qkv = (const float*)d_in[4];
  const float* w_out = (const float*)d_in[5];
  const float* b_out = (const float*)d_in[6];
  const float* ln2_g = (const float*)d_in[7];
  const float* ln2_b = (const float*)d_in[8];
  const float* w_fc1 = (const float*)d_in[9];
  const float* b_fc1 = (const float*)d_in[10];
  const float* w_fc2 = (const float*)d_in[11];
  const float* b_fc2 = (const float*)d_in[12];

  char* ws = (char*)d_ws;
  size_t off = 0;
  auto alloc = [&](size_t bytes) {
    void* p = ws + off;
    off = (off + bytes + 255) & ~(size_t)255;
    return p;
  };
  ushort_t* wqkvT = (ushort_t*)alloc((size_t)3 * C_DIM * C_DIM * 2);
  ushort_t* woutT = (ushort_t*)alloc((size_t)C_DIM * C_DIM * 2);
  ushort_t* wfc1T = (ushort_t*)alloc((size_t)4 * C_DIM * C_DIM * 2);
  ushort_t* wfc2T = (ushort_t*)alloc((size_t)C_DIM * 4 * C_DIM * 2);
  ushort_t* xn1   = (ushort_t*)alloc((size_t)T_SEQ * C_DIM * 2);
  ushort_t* qkv   = (ushort_t*)alloc((size_t)T_SEQ * 3 * C_DIM * 2);
  ushort_t* attnO = (ushort_t*)alloc((size_t)T_SEQ * C_DIM * 2);
  float*    x2    = (float*)   alloc((size_t)T_SEQ * C_DIM * 4);
  ushort_t* xn2   = (ushort_t*)alloc((size_t)T_SEQ * C_DIM * 2);
  ushort_t* hbuf  = (ushort_t*)alloc((size_t)T_SEQ * 4 * C_DIM * 2);
  (void)ws_size;
  // attention partials alias the x2/xn2/hbuf region (written only after merge)
  float* part_O  = (float*)x2;
  float* part_ml = (float*)((char*)x2 + (size_t)2560 * 4096 * 4);

  cast_transpose<<<dim3(96, 32),  256, 0, stream>>>(w_qkv, wqkvT, C_DIM, 3 * C_DIM);
  cast_transpose<<<dim3(32, 32),  256, 0, stream>>>(w_out, woutT, C_DIM, C_DIM);
  cast_transpose<<<dim3(128, 32), 256, 0, stream>>>(w_fc1, wfc1T, C_DIM, 4 * C_DIM);
  cast_transpose<<<dim3(32, 128), 256, 0, stream>>>(w_fc2, wfc2T, 4 * C_DIM, C_DIM);

  ln_kernel<<<dim3(T_SEQ), 256, 0, stream>>>(x, ln1_g, ln1_b, xn1);

  gemm_bt<false, false, false><<<dim3(24, 32), 256, 0, stream>>>(
      xn1, wqkvT, b_qkv, nullptr, nullptr, qkv, T_SEQ, 3 * C_DIM, C_DIM);

  attn_kernel<<<dim3(160, NH), 256, 0, stream>>>(qkv, part_O, part_ml);
  attn_merge<<<dim3(T_SEQ / 64, NH), 256, 0, stream>>>(part_O, part_ml, attnO);

  gemm_bt<false, true, true><<<dim3(8, 32), 256, 0, stream>>>(
      attnO, woutT, b_out, x, x2, nullptr, T_SEQ, C_DIM, C_DIM);

  ln_kernel<<<dim3(T_SEQ), 256, 0, stream>>>(x2, ln2_g, ln2_b, xn2);

  gemm_bt<true, false, false><<<dim3(32, 32), 256, 0, stream>>>(
      xn2, wfc1T, b_fc1, nullptr, nullptr, hbuf, T_SEQ, 4 * C_DIM, C_DIM);

  gemm_bt<false, true, true><<<dim3(8, 32), 256, 0, stream>>>(
      hbuf, wfc2T, b_fc2, x2, (float*)d_out, nullptr, T_SEQ, C_DIM, 4 * C_DIM);
}